// Round 6
// baseline (426.987 us; speedup 1.0000x reference)
//
#include <hip/hip_runtime.h>

#define NNODES 100000
#define NEDGES 1600000
#define FDIM 128
#define EDIM 32
#define NCLS 17
#define ROWU 16   // embed-only row: 16 u32 = 32 x f16 = 64 B = ONE cache line
#define WPK (16 * NCLS)   // packed half2 table entries per half (u- and v- tables)
#define SCB 1024          // scan block size
#define NSB ((NNODES + SCB - 1) / SCB)   // 98 scan blocks

typedef unsigned int u32;
typedef _Float16 h2 __attribute__((ext_vector_type(2)));

__device__ inline h2 bch(u32 x) { return __builtin_bit_cast(h2, x); }

// dot2: acc += a[0]*w[0] + a[1]*w[1], f32 accumulate
__device__ inline float dot2acc(h2 a, u32 wbits, float acc) {
#if __has_builtin(__builtin_amdgcn_fdot2)
  return __builtin_amdgcn_fdot2(a, bch(wbits), acc, false);
#else
  h2 w = bch(wbits);
  acc = fmaf((float)a[0], (float)w[0], acc);
  return fmaf((float)a[1], (float)w[1], acc);
#endif
}

// ---------------- Kernel P: pack W_trans into half2 tables ----------------
__global__ __launch_bounds__(256) void prep_kernel(
    const float* __restrict__ W_trans, u32* __restrict__ wpack)
{
  for (int x = threadIdx.x; x < 2 * WPK; x += 256) {
    int tab = x / WPK;
    int r   = x - tab * WPK;
    int k2  = r / NCLS, c = r - k2 * NCLS;
    int row0 = tab ? (EDIM + 2 * k2) : (2 * k2);
    float a = W_trans[row0 * NCLS + c];
    float b = W_trans[(row0 + 1) * NCLS + c];
    if (!tab) { a *= 0.5f; b *= 0.5f; }
    h2 p; p[0] = (_Float16)a; p[1] = (_Float16)b;
    wpack[x] = __builtin_bit_cast(u32, p);
  }
}

// ---------------- Kernel H: out-degree histogram ----------------
__global__ __launch_bounds__(256) void hist_kernel(
    const int* __restrict__ edges, u32* __restrict__ cnt)
{
  int i = blockIdx.x * 256 + threadIdx.x;     // handles edges 2i and 2i+1
  int4 e2 = ((const int4*)edges)[i];
  atomicAdd(cnt + e2.x, 1u);
  atomicAdd(cnt + e2.z, 1u);
}

// ---------------- Kernels S1..S3: exclusive prefix scan of cnt -> base, pos ----------------
__global__ __launch_bounds__(SCB) void scan1_kernel(
    const u32* __restrict__ cnt, u32* __restrict__ base, u32* __restrict__ btot)
{
  __shared__ u32 s[SCB];
  int tid = threadIdx.x;
  int idx = blockIdx.x * SCB + tid;
  u32 v = (idx < NNODES) ? cnt[idx] : 0u;
  s[tid] = v; __syncthreads();
  for (int off = 1; off < SCB; off <<= 1) {
    u32 t = (tid >= off) ? s[tid - off] : 0u; __syncthreads();
    s[tid] += t; __syncthreads();
  }
  if (idx < NNODES) base[idx] = s[tid] - v;            // block-local exclusive
  if (tid == SCB - 1) btot[blockIdx.x] = s[tid];
}

__global__ __launch_bounds__(128) void scan2_kernel(
    const u32* __restrict__ btot, u32* __restrict__ boff)
{
  __shared__ u32 s[128];
  int tid = threadIdx.x;
  u32 v = (tid < NSB) ? btot[tid] : 0u;
  s[tid] = v; __syncthreads();
  for (int off = 1; off < 128; off <<= 1) {
    u32 t = (tid >= off) ? s[tid - off] : 0u; __syncthreads();
    s[tid] += t; __syncthreads();
  }
  if (tid < NSB) boff[tid] = s[tid] - v;
}

__global__ __launch_bounds__(SCB) void scan3_kernel(
    u32* __restrict__ base, const u32* __restrict__ boff, u32* __restrict__ pos)
{
  int idx = blockIdx.x * SCB + threadIdx.x;
  if (idx < NNODES) {
    u32 b = base[idx] + boff[blockIdx.x];
    base[idx] = b;
    pos[idx]  = b;
  }
}

// ---------------- Kernel A: per-node embed only, 64-thread blocks ----------------
__global__ __launch_bounds__(64) void node_kernel(
    const float* __restrict__ features,
    const float* __restrict__ W_embed,   // [128][32]
    const float* __restrict__ b_embed,   // [32]
    u32* __restrict__ nodetab)
{
  int n = blockIdx.x * 64 + threadIdx.x;
  if (n >= NNODES) return;

  float acc[EDIM];
  #pragma unroll
  for (int c = 0; c < EDIM; ++c) acc[c] = b_embed[c];

  const float4* f4 = (const float4*)(features + (size_t)n * FDIM);
  for (int k4 = 0; k4 < FDIM / 4; ++k4) {
    float4 f = f4[k4];
    const float* w = W_embed + k4 * 4 * EDIM;   // uniform -> s_load
    #pragma unroll
    for (int c = 0; c < EDIM; ++c) {
      acc[c] = fmaf(f.x, w[c],            acc[c]);
      acc[c] = fmaf(f.y, w[EDIM + c],     acc[c]);
      acc[c] = fmaf(f.z, w[2 * EDIM + c], acc[c]);
      acc[c] = fmaf(f.w, w[3 * EDIM + c], acc[c]);
    }
  }

  u32 p[16];
  #pragma unroll
  for (int i = 0; i < 16; ++i) {
    h2 t; t[0] = (_Float16)acc[2 * i]; t[1] = (_Float16)acc[2 * i + 1];
    p[i] = __builtin_bit_cast(u32, t);
  }
  uint4* row = (uint4*)(nodetab + (size_t)n * ROWU);
  #pragma unroll
  for (int i = 0; i < 4; ++i)
    row[i] = make_uint4(p[4 * i], p[4 * i + 1], p[4 * i + 2], p[4 * i + 3]);
}

// ---------------- Kernel B: per-edge logits; exact-slot CSR scatter ----------------
// CSR region is 12.8 MB (8 B x NEDGES, no padding): scatter RFO + partial-line
// merge is absorbed by L3 instead of churning HBM (round-5 surplus ~190 MB).
// FAST=1: csr[atomicAdd(pos[src])] = (eid, w). FAST=0: fp32 atomic scatter tail.
template <int FAST>
__global__ __launch_bounds__(256, 4) void edge_kernel6(
    const int*   __restrict__ edges,
    const float* __restrict__ weights,
    const u32*   __restrict__ wpack,     // 2*WPK packed half2 (uniform -> s_load)
    const float* __restrict__ b_trans,   // [17]
    const u32*   __restrict__ nodetab,
    float* __restrict__ poss_edge,
    u32*   __restrict__ pos,             // FAST: running cursors (init = base)
    uint2* __restrict__ csr,             // FAST: compact CSR entries (eid, w_bits)
    float* __restrict__ recall)          // !FAST
{
  __shared__ float sOut[256 * NCLS];   // 17 KB staging for coalesced poss_edge store
  __shared__ int   sSrc[256];          // fallback tail only
  int tid = threadIdx.x;
  int e = blockIdx.x * 256 + tid;
  int2 ed = ((const int2*)edges)[e];
  int src = ed.x, dst = ed.y;

  const uint4* rs4 = (const uint4*)(nodetab + (size_t)src * ROWU);
  const uint4* rd4 = (const uint4*)(nodetab + (size_t)dst * ROWU);
  // hoist ALL row loads: one gather-latency round per edge
  uint4 sq[4] = {rs4[0], rs4[1], rs4[2], rs4[3]};
  uint4 dq[4] = {rd4[0], rd4[1], rd4[2], rd4[3]};
  float w = weights[e];

  if (FAST) {
    // exact-capacity CSR insert, issued early to overlap the math below
    u32 slot = atomicAdd(pos + src, 1u);
    csr[slot] = make_uint2((u32)e, __float_as_uint(w));
  }

  float lgt[NCLS];
  #pragma unroll
  for (int c = 0; c < NCLS; ++c) lgt[c] = b_trans[c];

  #pragma unroll
  for (int q = 0; q < 4; ++q) {
    u32 su[4] = {sq[q].x, sq[q].y, sq[q].z, sq[q].w};
    u32 du[4] = {dq[q].x, dq[q].y, dq[q].z, dq[q].w};
    #pragma unroll
    for (int j = 0; j < 4; ++j) {
      int k2 = q * 4 + j;
      h2 s2 = bch(su[j]), d2 = bch(du[j]);
      h2 uu = s2 + d2;                 // v_pk_add_f16 (0.5 folded into W1 table)
      h2 t  = s2 - d2;
      h2 vv = t * t;                   // v_pk_mul_f16
      const u32* w1 = wpack + k2 * NCLS;         // uniform -> s_load
      const u32* w2 = wpack + WPK + k2 * NCLS;
      #pragma unroll
      for (int c = 0; c < NCLS; ++c) {
        lgt[c] = dot2acc(uu, w1[c], lgt[c]);
        lgt[c] = dot2acc(vv, w2[c], lgt[c]);
      }
    }
  }

  float m = lgt[0];
  #pragma unroll
  for (int c = 1; c < NCLS; ++c) m = fmaxf(m, lgt[c]);
  float sum = 0.f;
  #pragma unroll
  for (int c = 0; c < NCLS; ++c) { lgt[c] = __expf(lgt[c] - m); sum += lgt[c]; }
  float inv = 1.0f / sum;

  #pragma unroll
  for (int c = 0; c < NCLS; ++c) sOut[tid * NCLS + c] = lgt[c] * inv;
  __syncthreads();

  // coalesced float4 poss_edge store
  float4* outp = (float4*)(poss_edge + (size_t)blockIdx.x * 256 * NCLS);
  const float4* sOut4 = (const float4*)sOut;
  for (int i = tid; i < 256 * NCLS / 4; i += 256)
    outp[i] = sOut4[i];

  if (!FAST) {
    __syncthreads();
    float wi = w * inv;
    sSrc[tid] = src;
    #pragma unroll
    for (int c = 0; c < NCLS; ++c) sOut[tid * NCLS + c] = lgt[c] * wi;
    __syncthreads();
    for (int i = tid; i < 256 * NCLS; i += 256) {
      unsigned e2 = (unsigned)i / NCLS;
      unsigned c2 = (unsigned)i - e2 * NCLS;
      atomicAdd(recall + (size_t)sSrc[e2] * NCLS + c2, sOut[i]);
    }
  }
}

// ---------------- Kernel R: CSR gather segment-sum + fused divide, 4-deep MLP ----------------
__global__ __launch_bounds__(256, 8) void reduce_kernel(
    const float* __restrict__ poss_edge,
    const u32*   __restrict__ cnt,
    const u32*   __restrict__ base,
    const uint2* __restrict__ csr,       // (eid, weight_bits), dense per node
    const float* __restrict__ nsum,
    float* __restrict__ recall,
    float* __restrict__ poss_node)
{
  int tid = threadIdx.x;
  if (tid >= 255) return;                 // 15 nodes x 17 classes
  int g = tid / 17;
  int n = blockIdx.x * 15 + g;
  if (n >= NNODES) return;
  int c = tid - g * 17;

  u32 deg = cnt[n];                       // exact: no capacity cap
  float ns = nsum[n];
  const uint2* bk = csr + base[n];

  float acc = 0.f;
  u32 k = 0;
  for (; k + 4 <= deg; k += 4) {
    uint2 b0 = bk[k], b1 = bk[k + 1], b2 = bk[k + 2], b3 = bk[k + 3];
    float p0 = poss_edge[(size_t)b0.x * NCLS + c];
    float p1 = poss_edge[(size_t)b1.x * NCLS + c];
    float p2 = poss_edge[(size_t)b2.x * NCLS + c];
    float p3 = poss_edge[(size_t)b3.x * NCLS + c];
    acc = fmaf(p0, __uint_as_float(b0.y), acc);
    acc = fmaf(p1, __uint_as_float(b1.y), acc);
    acc = fmaf(p2, __uint_as_float(b2.y), acc);
    acc = fmaf(p3, __uint_as_float(b3.y), acc);
  }
  for (; k < deg; ++k) {
    uint2 b = bk[k];
    acc = fmaf(poss_edge[(size_t)b.x * NCLS + c], __uint_as_float(b.y), acc);
  }

  size_t o = (size_t)n * NCLS + c;
  recall[o]    = acc;
  poss_node[o] = acc / ns;
}

// ---------------- Fallback divide ----------------
__global__ __launch_bounds__(256) void div_kernel(
    const float* __restrict__ recall,
    const float* __restrict__ nsum,
    float* __restrict__ poss_node)
{
  int i = blockIdx.x * 256 + threadIdx.x;
  if (i < NNODES * NCLS)
    poss_node[i] = recall[i] / nsum[i / NCLS];
}

extern "C" void kernel_launch(void* const* d_in, const int* in_sizes, int n_in,
                              void* d_out, int out_size, void* d_ws, size_t ws_size,
                              hipStream_t stream) {
  const float* features = (const float*)d_in[0];
  const int*   edges    = (const int*)d_in[1];
  const float* weights  = (const float*)d_in[2];
  const float* nsum     = (const float*)d_in[3];
  const float* W_embed  = (const float*)d_in[4];
  const float* b_embed  = (const float*)d_in[5];
  const float* W_trans  = (const float*)d_in[6];
  const float* b_trans  = (const float*)d_in[7];

  float* out       = (float*)d_out;
  float* poss_node = out;
  float* poss_edge = out + (size_t)NNODES * NCLS;
  float* recall    = out + (size_t)(NNODES + NEDGES) * NCLS;

  // workspace layout (u32 units): nodetab | wpack | cnt | base | pos | btot | boff | csr
  u32* nodetab = (u32*)d_ws;                         // 6.4 MB
  u32* wpack   = nodetab + (size_t)NNODES * ROWU;    // 2.2 KB
  u32* cnt     = wpack + 2 * WPK;                    // 400 KB
  u32* base    = cnt + NNODES;                       // 400 KB
  u32* pos     = base + NNODES;                      // 400 KB
  u32* btot    = pos + NNODES;                       // 512 B
  u32* boff    = btot + 128;                         // 512 B
  u32* csrw    = boff + 128;                         // 12.8 MB (uint2 x NEDGES)
  uint2* csr   = (uint2*)csrw;
  size_t need_fast = ((size_t)(csrw - (u32*)d_ws) + (size_t)NEDGES * 2) * 4;  // ~20.4 MB
  size_t need_min  = ((size_t)NNODES * ROWU + 2 * WPK) * 4;

  if (ws_size >= need_fast) {
    hipMemsetAsync(cnt, 0, (size_t)NNODES * sizeof(u32), stream);
    prep_kernel<<<1, 256, 0, stream>>>(W_trans, wpack);
    hist_kernel<<<NEDGES / 512, 256, 0, stream>>>(edges, cnt);
    scan1_kernel<<<NSB, SCB, 0, stream>>>(cnt, base, btot);
    scan2_kernel<<<1, 128, 0, stream>>>(btot, boff);
    scan3_kernel<<<NSB, SCB, 0, stream>>>(base, boff, pos);
    node_kernel<<<(NNODES + 63) / 64, 64, 0, stream>>>(features, W_embed, b_embed,
                                                       nodetab);
    edge_kernel6<1><<<NEDGES / 256, 256, 0, stream>>>(edges, weights, wpack, b_trans,
                                                      nodetab, poss_edge, pos, csr,
                                                      nullptr);
    reduce_kernel<<<(NNODES + 14) / 15, 256, 0, stream>>>(poss_edge, cnt, base, csr,
                                                          nsum, recall, poss_node);
  } else if (ws_size >= need_min) {
    // fallback: fp32 atomic scatter + separate divide (no CSR space)
    hipMemsetAsync(recall, 0, (size_t)NNODES * NCLS * sizeof(float), stream);
    prep_kernel<<<1, 256, 0, stream>>>(W_trans, wpack);
    node_kernel<<<(NNODES + 63) / 64, 64, 0, stream>>>(features, W_embed, b_embed,
                                                       nodetab);
    edge_kernel6<0><<<NEDGES / 256, 256, 0, stream>>>(edges, weights, wpack, b_trans,
                                                      nodetab, poss_edge, nullptr, nullptr,
                                                      recall);
    div_kernel<<<(NNODES * NCLS + 255) / 256, 256, 0, stream>>>(recall, nsum, poss_node);
  }
}